// Round 10
// baseline (252.917 us; speedup 1.0000x reference)
//
#include <hip/hip_runtime.h>

typedef __attribute__((ext_vector_type(8))) short short8;
typedef __attribute__((ext_vector_type(4))) float f32x4;
typedef __attribute__((ext_vector_type(4))) unsigned int u32x4;
typedef unsigned short u16;
typedef unsigned int u32;

#define MFMA16 __builtin_amdgcn_mfma_f32_16x16x32_bf16

static constexpr int TGT = 2048, SRCN = 2048, DIM = 1024, NH = 16;
static constexpr int NV = 32000, NTOT = 34000;
#define FLT_EPS 1.1920928955078125e-07f

__device__ __forceinline__ u16 f2bf(float f) {
  unsigned u = __float_as_uint(f);
  return (u16)((u + 0x7FFFu + ((u >> 16) & 1u)) >> 16);
}

// swizzled ushort index for a [64][64] bf16 LDS tile; seg = 16B segment (0..7)
__device__ __forceinline__ int swz8(int row, int seg) {
  return row * 64 + ((seg ^ (row & 7)) << 3);
}

// ---------------------------------------------------------------------------
// shared branch bodies
// ---------------------------------------------------------------------------
__device__ __forceinline__ void stats_row_body(
    int t, const float* __restrict__ logits, const float* __restrict__ tgt,
    const float* __restrict__ w_ptr, const float* __restrict__ b_ptr,
    float4* __restrict__ rowc, int tid, int lane, int w, float* red) {
  const f32x4* l4 = (const f32x4*)(logits + (size_t)t * NV);
  float e0 = 0.f, e1 = 0.f, e2 = 0.f, e3 = 0.f;
  const f32x4 z4 = {0.f, 0.f, 0.f, 0.f};
#pragma unroll 2
  for (int pk = 0; pk < 8; ++pk) {
    int g0 = pk * 1024 + tid;
    int g1 = g0 + 256, g2 = g0 + 512, g3 = g0 + 768;
    bool d0 = g0 < NV / 4, d1 = g1 < NV / 4, d2 = g2 < NV / 4, d3 = g3 < NV / 4;
    f32x4 v0 = d0 ? l4[g0] : z4;
    f32x4 v1 = d1 ? l4[g1] : z4;
    f32x4 v2 = d2 ? l4[g2] : z4;
    f32x4 v3 = d3 ? l4[g3] : z4;
    float s0 = (__expf(v0.x) + __expf(v0.y)) + (__expf(v0.z) + __expf(v0.w));
    float s1 = (__expf(v1.x) + __expf(v1.y)) + (__expf(v1.z) + __expf(v1.w));
    float s2 = (__expf(v2.x) + __expf(v2.y)) + (__expf(v2.z) + __expf(v2.w));
    float s3 = (__expf(v3.x) + __expf(v3.y)) + (__expf(v3.z) + __expf(v3.w));
    e0 += d0 ? s0 : 0.f;
    e1 += d1 ? s1 : 0.f;
    e2 += d2 ? s2 : 0.f;
    e3 += d3 ? s3 : 0.f;
  }
  float es = (e0 + e1) + (e2 + e3);

  float4 xv = *(const float4*)&tgt[(size_t)t * DIM + tid * 4];
  float4 wv = *(const float4*)&w_ptr[tid * 4];
  float g = (xv.x * wv.x + xv.y * wv.y) + (xv.z * wv.z + xv.w * wv.w);
  for (int d = 1; d < 64; d <<= 1) {
    es += __shfl_xor(es, d, 64);
    g += __shfl_xor(g, d, 64);
  }
  if (lane == 0) { red[w] = es; red[4 + w] = g; }
  __syncthreads();
  if (tid == 0) {
    float tot = red[0] + red[1] + red[2] + red[3];
    float gs = red[4] + red[5] + red[6] + red[7] + b_ptr[0];
    float c = 1.0f / (1.0f + __expf(-gs));
    float4 rc;
    rc.x = (1.0f - c) / tot;  // K1
    rc.y = c * FLT_EPS;       // Ceps
    rc.z = c;
    rc.w = 0.f;
    rowc[t] = rc;
  }
  __syncthreads();  // red[] safe for reuse (multi-row blocks)
}

// sort + rank assignment. segmap[id] = rank | count<<16 (0xFFFFFFFF absent);
// ustart[rank] = start_in_sorted | count<<16 (0xFFFFFFFF unused).
// scan[] aliases vv_ (dead after sperm copy) -> total LDS 16 KB.
__device__ __forceinline__ void sort_body(
    const int* __restrict__ ids, int* __restrict__ sperm,
    u32* __restrict__ segmap, u32* __restrict__ ustart,
    int tid, int lane, int w, char* smem) {
  int* kk_ = (int*)smem;             // 8 KB
  int* vv_ = (int*)(smem + 8192);    // 8 KB (scan aliases this after copy-out)
  for (int i = tid; i < 2048; i += 256) { kk_[i] = ids[i]; vv_[i] = i; }
  for (int i = tid; i < 2048; i += 256) ustart[i] = 0xFFFFFFFFu;
  __syncthreads();
  for (int kk = 2; kk <= 2048; kk <<= 1)
    for (int j = kk >> 1; j > 0; j >>= 1) {
      for (int m = tid; m < 1024; m += 256) {
        int i = ((m & ~(j - 1)) << 1) | (m & (j - 1));
        int l = i | j;
        bool asc = ((i & kk) == 0);
        int ki = kk_[i], kl = kk_[l];
        if ((ki > kl) == asc) {
          kk_[i] = kl; kk_[l] = ki;
          int tv = vv_[i]; vv_[i] = vv_[l]; vv_[l] = tv;
        }
      }
      __syncthreads();
    }
  for (int i = tid; i < 2048; i += 256) sperm[i] = vv_[i];
  for (int i = tid; i < NTOT; i += 256) segmap[i] = 0xFFFFFFFFu;
  __syncthreads();
  int* scan = vv_;  // alias: vv_ dead now
  if (tid == 0) scan[4] = 0;
  __syncthreads();
  // rank assignment: 8 chunks of 256, ballot-based prefix over heads
  for (int c = 0; c < 8; ++c) {
    int p = c * 256 + tid;
    int id = kk_[p];
    bool head = (p == 0) || (kk_[p - 1] != id);
    unsigned long long bal = __ballot(head);
    int lanepfx = __popcll(bal & ((1ull << lane) - 1ull));
    int wtot = __popcll(bal);
    if (lane == 0) scan[w] = wtot;
    __syncthreads();
    int woff = 0;
    for (int i = 0; i < w; ++i) woff += scan[i];
    int base = scan[4];
    if (head) {
      int q = p + 1;
      while (q < 2048 && kk_[q] == id) ++q;
      int rank = base + woff + lanepfx;
      u32 cnt = (u32)(q - p);
      segmap[id] = (u32)rank | (cnt << 16);
      ustart[rank] = (u32)p | (cnt << 16);
    }
    __syncthreads();
    if (tid == 0) scan[4] = base + scan[0] + scan[1] + scan[2] + scan[3];
    __syncthreads();
  }
}

// ---------------------------------------------------------------------------
// K1: both projections in one launch (blockIdx.z: 0 = Q from tgt, 1 = K from src)
// ---------------------------------------------------------------------------
__global__ __launch_bounds__(256) void proj_gemm(
    const float* __restrict__ Xq, const float* __restrict__ Wq,
    const float* __restrict__ Bq, u16* __restrict__ Cq,
    const float* __restrict__ Xk, const float* __restrict__ Wk,
    const float* __restrict__ Bk, u16* __restrict__ Ck) {
  const int zz = blockIdx.z;
  const float* X = zz ? Xk : Xq;
  const float* W = zz ? Wk : Wq;
  const float* bias = zz ? Bk : Bq;
  u16* C = zz ? Ck : Cq;
  const float scale = zz ? 1.0f : 0.125f;

  __shared__ u16 As[128 * 32];
  __shared__ u16 Bs[128 * 32];
  const int n0 = blockIdx.x * 128, m0 = blockIdx.y * 128;
  const int tid = threadIdx.x, lane = tid & 63, w = tid >> 6;
  const int wr = w >> 1, wc = w & 1;
  const int srow = tid >> 1, shalf = tid & 1;
  f32x4 acc[4][4] = {};

  for (int k0 = 0; k0 < DIM; k0 += 32) {
    __syncthreads();
    {
      const float* pa = X + (size_t)(m0 + srow) * DIM + k0 + shalf * 16;
      const float* pb = W + (size_t)(n0 + srow) * DIM + k0 + shalf * 16;
      float4 a0 = ((const float4*)pa)[0], a1 = ((const float4*)pa)[1];
      float4 a2 = ((const float4*)pa)[2], a3 = ((const float4*)pa)[3];
      float4 b0 = ((const float4*)pb)[0], b1 = ((const float4*)pb)[1];
      float4 b2 = ((const float4*)pb)[2], b3 = ((const float4*)pb)[3];
      short8 wa0, wa1, wb0, wb1;
      wa0[0]=(short)f2bf(a0.x); wa0[1]=(short)f2bf(a0.y); wa0[2]=(short)f2bf(a0.z); wa0[3]=(short)f2bf(a0.w);
      wa0[4]=(short)f2bf(a1.x); wa0[5]=(short)f2bf(a1.y); wa0[6]=(short)f2bf(a1.z); wa0[7]=(short)f2bf(a1.w);
      wa1[0]=(short)f2bf(a2.x); wa1[1]=(short)f2bf(a2.y); wa1[2]=(short)f2bf(a2.z); wa1[3]=(short)f2bf(a2.w);
      wa1[4]=(short)f2bf(a3.x); wa1[5]=(short)f2bf(a3.y); wa1[6]=(short)f2bf(a3.z); wa1[7]=(short)f2bf(a3.w);
      wb0[0]=(short)f2bf(b0.x); wb0[1]=(short)f2bf(b0.y); wb0[2]=(short)f2bf(b0.z); wb0[3]=(short)f2bf(b0.w);
      wb0[4]=(short)f2bf(b1.x); wb0[5]=(short)f2bf(b1.y); wb0[6]=(short)f2bf(b1.z); wb0[7]=(short)f2bf(b1.w);
      wb1[0]=(short)f2bf(b2.x); wb1[1]=(short)f2bf(b2.y); wb1[2]=(short)f2bf(b2.z); wb1[3]=(short)f2bf(b2.w);
      wb1[4]=(short)f2bf(b3.x); wb1[5]=(short)f2bf(b3.y); wb1[6]=(short)f2bf(b3.z); wb1[7]=(short)f2bf(b3.w);
      int swz = (srow >> 1) & 3;
      int sg0 = ((shalf * 2 + 0) ^ swz) << 3;
      int sg1 = ((shalf * 2 + 1) ^ swz) << 3;
      *(short8*)&As[srow * 32 + sg0] = wa0;
      *(short8*)&As[srow * 32 + sg1] = wa1;
      *(short8*)&Bs[srow * 32 + sg0] = wb0;
      *(short8*)&Bs[srow * 32 + sg1] = wb1;
    }
    __syncthreads();
    const int kq = lane >> 4;
    short8 af[4], bfr[4];
    for (int f = 0; f < 4; ++f) {
      int ar = wr * 64 + f * 16 + (lane & 15);
      af[f] = *(const short8*)&As[ar * 32 + ((kq ^ ((ar >> 1) & 3)) << 3)];
      int br = wc * 64 + f * 16 + (lane & 15);
      bfr[f] = *(const short8*)&Bs[br * 32 + ((kq ^ ((br >> 1) & 3)) << 3)];
    }
    for (int fr = 0; fr < 4; ++fr)
      for (int fc = 0; fc < 4; ++fc)
        acc[fr][fc] = MFMA16(af[fr], bfr[fc], acc[fr][fc], 0, 0, 0);
  }

  for (int fc = 0; fc < 4; ++fc) {
    int col = n0 + wc * 64 + fc * 16 + (lane & 15);
    float bv = bias[col];
    for (int fr = 0; fr < 4; ++fr)
      for (int r = 0; r < 4; ++r) {
        int rowm = m0 + wr * 64 + fr * 16 + ((lane >> 4) << 2) + r;
        C[(size_t)rowm * DIM + col] = f2bf((acc[fr][fc][r] + bv) * scale);
      }
  }
}

// ---------------------------------------------------------------------------
// K2: Zinv[h][t] = 1 / (16 * sum_s exp(score_h(t,s)))
// ---------------------------------------------------------------------------
__global__ __launch_bounds__(256) void zsum_kernel(const u16* __restrict__ Qb,
                                                   const u16* __restrict__ Kb,
                                                   float* __restrict__ Zinv) {
  __shared__ u16 Ks[64 * 64];
  const int h = blockIdx.x, t0 = blockIdx.y * 64;
  const int tid = threadIdx.x, lane = tid & 63, w = tid >> 6;
  const int arow = t0 + w * 16 + (lane & 15);
  const int acol = h * 64 + ((lane >> 4) << 3);
  short8 a0 = *(const short8*)&Qb[(size_t)arow * DIM + acol];
  short8 a1 = *(const short8*)&Qb[(size_t)arow * DIM + acol + 32];
  float zacc[4] = {0.f, 0.f, 0.f, 0.f};

  for (int s0 = 0; s0 < SRCN; s0 += 64) {
    __syncthreads();
    for (int q = tid; q < 512; q += 256) {
      int r = q >> 3, seg = q & 7;
      *(short8*)&Ks[swz8(r, seg)] = *(const short8*)&Kb[(size_t)(s0 + r) * DIM + h * 64 + seg * 8];
    }
    __syncthreads();
    for (int sub = 0; sub < 4; ++sub) {
      int brow = sub * 16 + (lane & 15);
      int slo = (lane >> 4);
      short8 b0 = *(const short8*)&Ks[swz8(brow, slo)];
      short8 b1 = *(const short8*)&Ks[swz8(brow, slo + 4)];
      f32x4 c = {0.f, 0.f, 0.f, 0.f};
      c = MFMA16(a0, b0, c, 0, 0, 0);
      c = MFMA16(a1, b1, c, 0, 0, 0);
      zacc[0] += __expf(c[0]); zacc[1] += __expf(c[1]);
      zacc[2] += __expf(c[2]); zacc[3] += __expf(c[3]);
    }
  }
  for (int d = 1; d < 16; d <<= 1) {
    zacc[0] += __shfl_xor(zacc[0], d, 64);
    zacc[1] += __shfl_xor(zacc[1], d, 64);
    zacc[2] += __shfl_xor(zacc[2], d, 64);
    zacc[3] += __shfl_xor(zacc[3], d, 64);
  }
  if ((lane & 15) == 0) {
    int trow = t0 + w * 16 + ((lane >> 4) << 2);
    for (int r = 0; r < 4; ++r)
      Zinv[h * TGT + trow + r] = 1.0f / (16.0f * zacc[r]);
  }
}

// ---------------------------------------------------------------------------
// K3: heterogeneous fused launch, 16 KB LDS, EXACTLY 2048 blocks (single
// generation at 8 blocks/CU wave cap).
// block 0: sort+rank; blocks 1..1024: attn tiles; blocks 1025..2047: stats
// (2 rows each; block 1025 takes the 2 leftover rows too).
// ---------------------------------------------------------------------------
__global__ __launch_bounds__(256) void fused_mid_kernel(
    const u16* __restrict__ Qb, const u16* __restrict__ Kb,
    const float* __restrict__ Zinv, float* __restrict__ attn,
    const float* __restrict__ logits, const float* __restrict__ tgt,
    const float* __restrict__ w_ptr, const float* __restrict__ b_ptr,
    const int* __restrict__ ids, int* __restrict__ sperm,
    u32* __restrict__ segmap, u32* __restrict__ ustart,
    float4* __restrict__ rowc) {
  __shared__ __align__(16) char smem[16384];
  const int b = blockIdx.x;
  const int tid = threadIdx.x, lane = tid & 63, w = tid >> 6;

  if (b == 0) {
    sort_body(ids, sperm, segmap, ustart, tid, lane, w, smem);
    return;
  }
  if (b > 1024) {
    const int j = b - 1025;  // 0..1022
    stats_row_body(j * 2, logits, tgt, w_ptr, b_ptr, rowc, tid, lane, w, (float*)smem);
    stats_row_body(j * 2 + 1, logits, tgt, w_ptr, b_ptr, rowc, tid, lane, w, (float*)smem);
    if (j == 0) {
      stats_row_body(2046, logits, tgt, w_ptr, b_ptr, rowc, tid, lane, w, (float*)smem);
      stats_row_body(2047, logits, tgt, w_ptr, b_ptr, rowc, tid, lane, w, (float*)smem);
    }
    return;
  }
  // ---- attn tile (Zinv from global, 16 KB LDS) ----
  u16* Qs = (u16*)smem;           // 8 KB
  u16* Ks = (u16*)(smem + 8192);  // 8 KB
  const int bb = b - 1;
  const int s0 = (bb & 31) * 64, t0 = (bb >> 5) * 64;
  const int wr = w >> 1, wc = w & 1;
  f32x4 acc[2][2] = {};

  for (int h = 0; h < NH; ++h) {
    __syncthreads();
    for (int q = tid; q < 512; q += 256) {
      int r = q >> 3, seg = q & 7;
      *(short8*)&Qs[swz8(r, seg)] = *(const short8*)&Qb[(size_t)(t0 + r) * DIM + h * 64 + seg * 8];
      *(short8*)&Ks[swz8(r, seg)] = *(const short8*)&Kb[(size_t)(s0 + r) * DIM + h * 64 + seg * 8];
    }
    __syncthreads();
    f32x4 sc[2][2] = {};
    for (int kk = 0; kk < 2; ++kk) {
      int seg = (lane >> 4) + kk * 4;
      short8 a0 = *(const short8*)&Qs[swz8(wr * 32 + (lane & 15), seg)];
      short8 a1 = *(const short8*)&Qs[swz8(wr * 32 + 16 + (lane & 15), seg)];
      short8 b0 = *(const short8*)&Ks[swz8(wc * 32 + (lane & 15), seg)];
      short8 b1 = *(const short8*)&Ks[swz8(wc * 32 + 16 + (lane & 15), seg)];
      sc[0][0] = MFMA16(a0, b0, sc[0][0], 0, 0, 0);
      sc[0][1] = MFMA16(a0, b1, sc[0][1], 0, 0, 0);
      sc[1][0] = MFMA16(a1, b0, sc[1][0], 0, 0, 0);
      sc[1][1] = MFMA16(a1, b1, sc[1][1], 0, 0, 0);
    }
    for (int fr = 0; fr < 2; ++fr) {
      int trow = t0 + wr * 32 + fr * 16 + ((lane >> 4) << 2);
      float4 z4 = *(const float4*)&Zinv[h * TGT + trow];
      float iz[4] = {z4.x, z4.y, z4.z, z4.w};
      for (int fc = 0; fc < 2; ++fc)
        for (int r = 0; r < 4; ++r)
          acc[fr][fc][r] += __expf(sc[fr][fc][r]) * iz[r];
    }
  }
  for (int fr = 0; fr < 2; ++fr)
    for (int fc = 0; fc < 2; ++fc)
      for (int r = 0; r < 4; ++r) {
        int t = t0 + wr * 32 + fr * 16 + ((lane >> 4) << 2) + r;
        int s = s0 + wc * 32 + fc * 16 + (lane & 15);
        attn[(size_t)t * SRCN + s] = acc[fr][fc][r];
      }
}

// ---------------------------------------------------------------------------
// K4: dense output. One block per row (reversed), 512 threads.
// Phase 1 (short): stage attn row in LDS; compute pL[rank] via LDS gathers.
// Phase 2: pure stream — psum is a single predicated LDS read.
// ---------------------------------------------------------------------------
__global__ __launch_bounds__(512) void out_kernel(
    const float* __restrict__ logits, const float4* __restrict__ rowc,
    const int* __restrict__ sperm, const u32* __restrict__ segmap,
    const u32* __restrict__ ustart, const float* __restrict__ attn,
    float* __restrict__ out) {
  __shared__ float aL[2048];
  __shared__ float pL[2048];
  const int t = (TGT - 1) - blockIdx.x;
  const int tid = threadIdx.x;
  float4 rc = rowc[t];
  const float K1 = rc.x, Ceps = rc.y, cc = rc.z;
  const f32x4* l4 = (const f32x4*)(logits + (size_t)t * NV);
  f32x4* o4 = (f32x4*)(out + (size_t)t * NTOT);
  const u32x4* m4 = (const u32x4*)segmap;

  // phase 1: attn row -> LDS, then per-rank pointer sums
  *(float4*)&aL[tid * 4] = *(const float4*)&attn[(size_t)t * SRCN + tid * 4];
  __syncthreads();
  for (int r = tid; r < 2048; r += 512) {
    u32 u = ustart[r];
    if (u != 0xFFFFFFFFu) {
      int p = (int)(u & 0xFFFFu), n = (int)(u >> 16);
      float s = 0.f;
      for (int k = 0; k < n; ++k) s += aL[sperm[p + k]];
      pL[r] = cc * s;
    }
  }
  __syncthreads();

  auto psum = [&](u32 mv) -> float {
    return (mv == 0xFFFFFFFFu) ? Ceps : pL[mv & 0xFFFFu];
  };
  auto elem = [&](float v, bool d, u32 mv) -> float {
    float e = d ? __expf(v) : 0.f;
    return __logf(fmaf(e, K1, psum(mv)));
  };

  const f32x4 z4 = {0.f, 0.f, 0.f, 0.f};
#pragma unroll
  for (int pk = 0; pk < 4; ++pk) {
    int g0 = pk * 2048 + tid;
    int g1 = g0 + 512, g2 = g0 + 1024, g3 = g0 + 1536;
    u32x4 m0 = m4[g0], m1 = m4[g1], m2 = m4[g2], m3 = m4[g3];
    bool d0 = g0 < NV / 4, d1 = g1 < NV / 4, d2 = g2 < NV / 4, d3 = g3 < NV / 4;
    f32x4 v0 = d0 ? __builtin_nontemporal_load(&l4[g0]) : z4;
    f32x4 v1 = d1 ? __builtin_nontemporal_load(&l4[g1]) : z4;
    f32x4 v2 = d2 ? __builtin_nontemporal_load(&l4[g2]) : z4;
    f32x4 v3 = d3 ? __builtin_nontemporal_load(&l4[g3]) : z4;
    f32x4 o0, o1, o2, o3;
    o0.x = elem(v0.x, d0, m0.x); o0.y = elem(v0.y, d0, m0.y);
    o0.z = elem(v0.z, d0, m0.z); o0.w = elem(v0.w, d0, m0.w);
    o1.x = elem(v1.x, d1, m1.x); o1.y = elem(v1.y, d1, m1.y);
    o1.z = elem(v1.z, d1, m1.z); o1.w = elem(v1.w, d1, m1.w);
    o2.x = elem(v2.x, d2, m2.x); o2.y = elem(v2.y, d2, m2.y);
    o2.z = elem(v2.z, d2, m2.z); o2.w = elem(v2.w, d2, m2.w);
    o3.x = elem(v3.x, d3, m3.x); o3.y = elem(v3.y, d3, m3.y);
    o3.z = elem(v3.z, d3, m3.z); o3.w = elem(v3.w, d3, m3.w);
    __builtin_nontemporal_store(o0, &o4[g0]);
    __builtin_nontemporal_store(o1, &o4[g1]);
    __builtin_nontemporal_store(o2, &o4[g2]);
    __builtin_nontemporal_store(o3, &o4[g3]);
  }
  for (int g = 8192 + tid; g < NTOT / 4; g += 512) {
    u32x4 m = m4[g];
    f32x4 o;
    o.x = __logf(psum(m.x));
    o.y = __logf(psum(m.y));
    o.z = __logf(psum(m.z));
    o.w = __logf(psum(m.w));
    __builtin_nontemporal_store(o, &o4[g]);
  }
}

// ---------------------------------------------------------------------------
extern "C" void kernel_launch(void* const* d_in, const int* in_sizes, int n_in,
                              void* d_out, int out_size, void* d_ws, size_t ws_size,
                              hipStream_t stream) {
  const float* logits = (const float*)d_in[0];
  const int* ids      = (const int*)d_in[1];
  const float* src    = (const float*)d_in[2];
  const float* tgt    = (const float*)d_in[3];
  const float* w_q    = (const float*)d_in[4];
  const float* b_q    = (const float*)d_in[5];
  const float* w_k    = (const float*)d_in[6];
  const float* b_k    = (const float*)d_in[7];
  const float* w_ptr  = (const float*)d_in[8];
  const float* b_ptr  = (const float*)d_in[9];
  float* out = (float*)d_out;

  char* ws = (char*)d_ws;
  u16* Qb     = (u16*)(ws);                                       // 4 MiB
  u16* Kb     = (u16*)(ws + (size_t)4 * 1024 * 1024);             // 4 MiB
  float* Zinv = (float*)(ws + (size_t)8 * 1024 * 1024);           // 128 KiB
  float* attn = (float*)(ws + (size_t)8 * 1024 * 1024 + 131072);  // 16 MiB
  size_t tail_off = (size_t)8 * 1024 * 1024 + 131072 + (size_t)16 * 1024 * 1024;
  int* sperm   = (int*)(ws + tail_off);                      // 8 KiB
  u32* segmap  = (u32*)(ws + tail_off + 8192);               // 136 KiB
  u32* ustart  = (u32*)(ws + tail_off + 8192 + 136000);      // 8 KiB
  float4* rowc = (float4*)(ws + tail_off + 8192 + 136000 + 8192);  // 32 KiB

  proj_gemm<<<dim3(8, 16, 2), 256, 0, stream>>>(tgt, w_q, b_q, Qb, src, w_k, b_k, Kb);
  zsum_kernel<<<dim3(16, 32), 256, 0, stream>>>(Qb, Kb, Zinv);
  fused_mid_kernel<<<2048, 256, 0, stream>>>(Qb, Kb, Zinv, attn, logits, tgt,
                                             w_ptr, b_ptr, ids, sperm, segmap,
                                             ustart, rowc);
  out_kernel<<<TGT, 512, 0, stream>>>(logits, rowc, sperm, segmap, ustart, attn, out);
}

// Round 11
// 223.823 us; speedup vs baseline: 1.1300x; 1.1300x over previous
//
#include <hip/hip_runtime.h>

typedef __attribute__((ext_vector_type(8))) short short8;
typedef __attribute__((ext_vector_type(4))) float f32x4;
typedef __attribute__((ext_vector_type(4))) unsigned int u32x4;
typedef unsigned short u16;
typedef unsigned int u32;

#define MFMA16 __builtin_amdgcn_mfma_f32_16x16x32_bf16

static constexpr int TGT = 2048, SRCN = 2048, DIM = 1024, NH = 16;
static constexpr int NV = 32000, NTOT = 34000;
#define FLT_EPS 1.1920928955078125e-07f

__device__ __forceinline__ u16 f2bf(float f) {
  unsigned u = __float_as_uint(f);
  return (u16)((u + 0x7FFFu + ((u >> 16) & 1u)) >> 16);
}

// swizzled ushort index for a [64][64] bf16 LDS tile; seg = 16B segment (0..7)
__device__ __forceinline__ int swz8(int row, int seg) {
  return row * 64 + ((seg ^ (row & 7)) << 3);
}

// ---------------------------------------------------------------------------
// branch bodies
// ---------------------------------------------------------------------------
__device__ __forceinline__ void stats_row_body(
    int t, const float* __restrict__ logits, const float* __restrict__ tgt,
    const float* __restrict__ w_ptr, const float* __restrict__ b_ptr,
    float4* __restrict__ rowc, int tid, int lane, int w, float* red) {
  const f32x4* l4 = (const f32x4*)(logits + (size_t)t * NV);
  float e0 = 0.f, e1 = 0.f, e2 = 0.f, e3 = 0.f;
  const f32x4 z4 = {0.f, 0.f, 0.f, 0.f};
#pragma unroll 2
  for (int pk = 0; pk < 8; ++pk) {
    int g0 = pk * 1024 + tid;
    int g1 = g0 + 256, g2 = g0 + 512, g3 = g0 + 768;
    bool d0 = g0 < NV / 4, d1 = g1 < NV / 4, d2 = g2 < NV / 4, d3 = g3 < NV / 4;
    f32x4 v0 = d0 ? l4[g0] : z4;
    f32x4 v1 = d1 ? l4[g1] : z4;
    f32x4 v2 = d2 ? l4[g2] : z4;
    f32x4 v3 = d3 ? l4[g3] : z4;
    float s0 = (__expf(v0.x) + __expf(v0.y)) + (__expf(v0.z) + __expf(v0.w));
    float s1 = (__expf(v1.x) + __expf(v1.y)) + (__expf(v1.z) + __expf(v1.w));
    float s2 = (__expf(v2.x) + __expf(v2.y)) + (__expf(v2.z) + __expf(v2.w));
    float s3 = (__expf(v3.x) + __expf(v3.y)) + (__expf(v3.z) + __expf(v3.w));
    e0 += d0 ? s0 : 0.f;
    e1 += d1 ? s1 : 0.f;
    e2 += d2 ? s2 : 0.f;
    e3 += d3 ? s3 : 0.f;
  }
  float es = (e0 + e1) + (e2 + e3);

  float4 xv = *(const float4*)&tgt[(size_t)t * DIM + tid * 4];
  float4 wv = *(const float4*)&w_ptr[tid * 4];
  float g = (xv.x * wv.x + xv.y * wv.y) + (xv.z * wv.z + xv.w * wv.w);
  for (int d = 1; d < 64; d <<= 1) {
    es += __shfl_xor(es, d, 64);
    g += __shfl_xor(g, d, 64);
  }
  if (lane == 0) { red[w] = es; red[4 + w] = g; }
  __syncthreads();
  if (tid == 0) {
    float tot = red[0] + red[1] + red[2] + red[3];
    float gs = red[4] + red[5] + red[6] + red[7] + b_ptr[0];
    float c = 1.0f / (1.0f + __expf(-gs));
    float4 rc;
    rc.x = (1.0f - c) / tot;  // K1
    rc.y = c * FLT_EPS;       // Ceps
    rc.z = c;
    rc.w = 0.f;
    rowc[t] = rc;
  }
}

// sort + rank assignment. segmap[id] = rank | count<<16 (0xFFFFFFFF absent);
// ustart[rank] = start_in_sorted | count<<16 (0xFFFFFFFF unused).
__device__ __forceinline__ void sort_body(
    const int* __restrict__ ids, int* __restrict__ sperm,
    u32* __restrict__ segmap, u32* __restrict__ ustart,
    int tid, int lane, int w, char* smem) {
  int* kk_ = (int*)smem;             // 8 KB
  int* vv_ = (int*)(smem + 8192);    // 8 KB (scan aliases this after copy-out)
  for (int i = tid; i < 2048; i += 256) { kk_[i] = ids[i]; vv_[i] = i; }
  for (int i = tid; i < 2048; i += 256) ustart[i] = 0xFFFFFFFFu;
  __syncthreads();
  for (int kk = 2; kk <= 2048; kk <<= 1)
    for (int j = kk >> 1; j > 0; j >>= 1) {
      for (int m = tid; m < 1024; m += 256) {
        int i = ((m & ~(j - 1)) << 1) | (m & (j - 1));
        int l = i | j;
        bool asc = ((i & kk) == 0);
        int ki = kk_[i], kl = kk_[l];
        if ((ki > kl) == asc) {
          kk_[i] = kl; kk_[l] = ki;
          int tv = vv_[i]; vv_[i] = vv_[l]; vv_[l] = tv;
        }
      }
      __syncthreads();
    }
  for (int i = tid; i < 2048; i += 256) sperm[i] = vv_[i];
  for (int i = tid; i < NTOT; i += 256) segmap[i] = 0xFFFFFFFFu;
  __syncthreads();
  int* scan = vv_;  // alias: vv_ dead now
  if (tid == 0) scan[4] = 0;
  __syncthreads();
  for (int c = 0; c < 8; ++c) {
    int p = c * 256 + tid;
    int id = kk_[p];
    bool head = (p == 0) || (kk_[p - 1] != id);
    unsigned long long bal = __ballot(head);
    int lanepfx = __popcll(bal & ((1ull << lane) - 1ull));
    int wtot = __popcll(bal);
    if (lane == 0) scan[w] = wtot;
    __syncthreads();
    int woff = 0;
    for (int i = 0; i < w; ++i) woff += scan[i];
    int base = scan[4];
    if (head) {
      int q = p + 1;
      while (q < 2048 && kk_[q] == id) ++q;
      int rank = base + woff + lanepfx;
      u32 cnt = (u32)(q - p);
      segmap[id] = (u32)rank | (cnt << 16);
      ustart[rank] = (u32)p | (cnt << 16);
    }
    __syncthreads();
    if (tid == 0) scan[4] = base + scan[0] + scan[1] + scan[2] + scan[3];
    __syncthreads();
  }
}

__device__ __forceinline__ void proj_body(
    int bb, const float* __restrict__ Xq, const float* __restrict__ Wq,
    const float* __restrict__ Bq, u16* __restrict__ Cq,
    const float* __restrict__ Xk, const float* __restrict__ Wk,
    const float* __restrict__ Bk, u16* __restrict__ Ck,
    int tid, int lane, int w, char* smem) {
  const int zz = bb >> 7;
  const float* X = zz ? Xk : Xq;
  const float* W = zz ? Wk : Wq;
  const float* bias = zz ? Bk : Bq;
  u16* C = zz ? Ck : Cq;
  const float scale = zz ? 1.0f : 0.125f;

  u16* As = (u16*)smem;           // 8 KB
  u16* Bs = (u16*)(smem + 8192);  // 8 KB
  const int n0 = (bb & 7) * 128, m0 = ((bb >> 3) & 15) * 128;
  const int wr = w >> 1, wc = w & 1;
  const int srow = tid >> 1, shalf = tid & 1;
  f32x4 acc[4][4] = {};

  for (int k0 = 0; k0 < DIM; k0 += 32) {
    __syncthreads();
    {
      const float* pa = X + (size_t)(m0 + srow) * DIM + k0 + shalf * 16;
      const float* pb = W + (size_t)(n0 + srow) * DIM + k0 + shalf * 16;
      float4 a0 = ((const float4*)pa)[0], a1 = ((const float4*)pa)[1];
      float4 a2 = ((const float4*)pa)[2], a3 = ((const float4*)pa)[3];
      float4 b0 = ((const float4*)pb)[0], b1 = ((const float4*)pb)[1];
      float4 b2 = ((const float4*)pb)[2], b3 = ((const float4*)pb)[3];
      short8 wa0, wa1, wb0, wb1;
      wa0[0]=(short)f2bf(a0.x); wa0[1]=(short)f2bf(a0.y); wa0[2]=(short)f2bf(a0.z); wa0[3]=(short)f2bf(a0.w);
      wa0[4]=(short)f2bf(a1.x); wa0[5]=(short)f2bf(a1.y); wa0[6]=(short)f2bf(a1.z); wa0[7]=(short)f2bf(a1.w);
      wa1[0]=(short)f2bf(a2.x); wa1[1]=(short)f2bf(a2.y); wa1[2]=(short)f2bf(a2.z); wa1[3]=(short)f2bf(a2.w);
      wa1[4]=(short)f2bf(a3.x); wa1[5]=(short)f2bf(a3.y); wa1[6]=(short)f2bf(a3.z); wa1[7]=(short)f2bf(a3.w);
      wb0[0]=(short)f2bf(b0.x); wb0[1]=(short)f2bf(b0.y); wb0[2]=(short)f2bf(b0.z); wb0[3]=(short)f2bf(b0.w);
      wb0[4]=(short)f2bf(b1.x); wb0[5]=(short)f2bf(b1.y); wb0[6]=(short)f2bf(b1.z); wb0[7]=(short)f2bf(b1.w);
      wb1[0]=(short)f2bf(b2.x); wb1[1]=(short)f2bf(b2.y); wb1[2]=(short)f2bf(b2.z); wb1[3]=(short)f2bf(b2.w);
      wb1[4]=(short)f2bf(b3.x); wb1[5]=(short)f2bf(b3.y); wb1[6]=(short)f2bf(b3.z); wb1[7]=(short)f2bf(b3.w);
      int swz = (srow >> 1) & 3;
      int sg0 = ((shalf * 2 + 0) ^ swz) << 3;
      int sg1 = ((shalf * 2 + 1) ^ swz) << 3;
      *(short8*)&As[srow * 32 + sg0] = wa0;
      *(short8*)&As[srow * 32 + sg1] = wa1;
      *(short8*)&Bs[srow * 32 + sg0] = wb0;
      *(short8*)&Bs[srow * 32 + sg1] = wb1;
    }
    __syncthreads();
    const int kq = lane >> 4;
    short8 af[4], bfr[4];
    for (int f = 0; f < 4; ++f) {
      int ar = wr * 64 + f * 16 + (lane & 15);
      af[f] = *(const short8*)&As[ar * 32 + ((kq ^ ((ar >> 1) & 3)) << 3)];
      int br = wc * 64 + f * 16 + (lane & 15);
      bfr[f] = *(const short8*)&Bs[br * 32 + ((kq ^ ((br >> 1) & 3)) << 3)];
    }
    for (int fr = 0; fr < 4; ++fr)
      for (int fc = 0; fc < 4; ++fc)
        acc[fr][fc] = MFMA16(af[fr], bfr[fc], acc[fr][fc], 0, 0, 0);
  }

  for (int fc = 0; fc < 4; ++fc) {
    int col = n0 + wc * 64 + fc * 16 + (lane & 15);
    float bv = bias[col];
    for (int fr = 0; fr < 4; ++fr)
      for (int r = 0; r < 4; ++r) {
        int rowm = m0 + wr * 64 + fr * 16 + ((lane >> 4) << 2) + r;
        C[(size_t)rowm * DIM + col] = f2bf((acc[fr][fc][r] + bv) * scale);
      }
  }
}

// ---------------------------------------------------------------------------
// L1: heterogeneous {proj (MFMA) || sort || stats (HBM stream)} — disjoint pipes.
// blocks 0..255: proj; 256: sort; 257..2304: stats row t = b-257.
// ---------------------------------------------------------------------------
__global__ __launch_bounds__(256) void fused_a_kernel(
    const float* __restrict__ logits, const float* __restrict__ tgt,
    const float* __restrict__ src,
    const float* __restrict__ w_q, const float* __restrict__ b_q,
    const float* __restrict__ w_k, const float* __restrict__ b_k,
    const float* __restrict__ w_ptr, const float* __restrict__ b_ptr,
    const int* __restrict__ ids,
    u16* __restrict__ Qb, u16* __restrict__ Kb,
    int* __restrict__ sperm, u32* __restrict__ segmap,
    u32* __restrict__ ustart, float4* __restrict__ rowc) {
  __shared__ __align__(16) char smem[16384];
  const int b = blockIdx.x;
  const int tid = threadIdx.x, lane = tid & 63, w = tid >> 6;

  if (b < 256) {
    proj_body(b, tgt, w_q, b_q, Qb, src, w_k, b_k, Kb, tid, lane, w, smem);
  } else if (b == 256) {
    sort_body(ids, sperm, segmap, ustart, tid, lane, w, smem);
  } else {
    stats_row_body(b - 257, logits, tgt, w_ptr, b_ptr, rowc, tid, lane, w, (float*)smem);
  }
}

// ---------------------------------------------------------------------------
// L2: Zinv[h][t] = 1 / (16 * sum_s exp(score_h(t,s)))
// ---------------------------------------------------------------------------
__global__ __launch_bounds__(256) void zsum_kernel(const u16* __restrict__ Qb,
                                                   const u16* __restrict__ Kb,
                                                   float* __restrict__ Zinv) {
  __shared__ u16 Ks[64 * 64];
  const int h = blockIdx.x, t0 = blockIdx.y * 64;
  const int tid = threadIdx.x, lane = tid & 63, w = tid >> 6;
  const int arow = t0 + w * 16 + (lane & 15);
  const int acol = h * 64 + ((lane >> 4) << 3);
  short8 a0 = *(const short8*)&Qb[(size_t)arow * DIM + acol];
  short8 a1 = *(const short8*)&Qb[(size_t)arow * DIM + acol + 32];
  float zacc[4] = {0.f, 0.f, 0.f, 0.f};

  for (int s0 = 0; s0 < SRCN; s0 += 64) {
    __syncthreads();
    for (int q = tid; q < 512; q += 256) {
      int r = q >> 3, seg = q & 7;
      *(short8*)&Ks[swz8(r, seg)] = *(const short8*)&Kb[(size_t)(s0 + r) * DIM + h * 64 + seg * 8];
    }
    __syncthreads();
    for (int sub = 0; sub < 4; ++sub) {
      int brow = sub * 16 + (lane & 15);
      int slo = (lane >> 4);
      short8 b0 = *(const short8*)&Ks[swz8(brow, slo)];
      short8 b1 = *(const short8*)&Ks[swz8(brow, slo + 4)];
      f32x4 c = {0.f, 0.f, 0.f, 0.f};
      c = MFMA16(a0, b0, c, 0, 0, 0);
      c = MFMA16(a1, b1, c, 0, 0, 0);
      zacc[0] += __expf(c[0]); zacc[1] += __expf(c[1]);
      zacc[2] += __expf(c[2]); zacc[3] += __expf(c[3]);
    }
  }
  for (int d = 1; d < 16; d <<= 1) {
    zacc[0] += __shfl_xor(zacc[0], d, 64);
    zacc[1] += __shfl_xor(zacc[1], d, 64);
    zacc[2] += __shfl_xor(zacc[2], d, 64);
    zacc[3] += __shfl_xor(zacc[3], d, 64);
  }
  if ((lane & 15) == 0) {
    int trow = t0 + w * 16 + ((lane >> 4) << 2);
    for (int r = 0; r < 4; ++r)
      Zinv[h * TGT + trow + r] = 1.0f / (16.0f * zacc[r]);
  }
}

// ---------------------------------------------------------------------------
// L3: attn[t][s] = sum_h exp(score_h(t,s)) * Zinv[h][t] — full machine.
// ---------------------------------------------------------------------------
__global__ __launch_bounds__(256) void attn_kernel(
    const u16* __restrict__ Qb, const u16* __restrict__ Kb,
    const float* __restrict__ Zinv, float* __restrict__ attn) {
  __shared__ __align__(16) char smem[16384];
  u16* Qs = (u16*)smem;           // 8 KB
  u16* Ks = (u16*)(smem + 8192);  // 8 KB
  const int bb = blockIdx.x;
  const int s0 = (bb & 31) * 64, t0 = (bb >> 5) * 64;
  const int tid = threadIdx.x, lane = tid & 63, w = tid >> 6;
  const int wr = w >> 1, wc = w & 1;
  f32x4 acc[2][2] = {};

  for (int h = 0; h < NH; ++h) {
    __syncthreads();
    for (int q = tid; q < 512; q += 256) {
      int r = q >> 3, seg = q & 7;
      *(short8*)&Qs[swz8(r, seg)] = *(const short8*)&Qb[(size_t)(t0 + r) * DIM + h * 64 + seg * 8];
      *(short8*)&Ks[swz8(r, seg)] = *(const short8*)&Kb[(size_t)(s0 + r) * DIM + h * 64 + seg * 8];
    }
    __syncthreads();
    f32x4 sc[2][2] = {};
    for (int kk = 0; kk < 2; ++kk) {
      int seg = (lane >> 4) + kk * 4;
      short8 a0 = *(const short8*)&Qs[swz8(wr * 32 + (lane & 15), seg)];
      short8 a1 = *(const short8*)&Qs[swz8(wr * 32 + 16 + (lane & 15), seg)];
      short8 b0 = *(const short8*)&Ks[swz8(wc * 32 + (lane & 15), seg)];
      short8 b1 = *(const short8*)&Ks[swz8(wc * 32 + 16 + (lane & 15), seg)];
      sc[0][0] = MFMA16(a0, b0, sc[0][0], 0, 0, 0);
      sc[0][1] = MFMA16(a0, b1, sc[0][1], 0, 0, 0);
      sc[1][0] = MFMA16(a1, b0, sc[1][0], 0, 0, 0);
      sc[1][1] = MFMA16(a1, b1, sc[1][1], 0, 0, 0);
    }
    for (int fr = 0; fr < 2; ++fr) {
      int trow = t0 + wr * 32 + fr * 16 + ((lane >> 4) << 2);
      float4 z4 = *(const float4*)&Zinv[h * TGT + trow];
      float iz[4] = {z4.x, z4.y, z4.z, z4.w};
      for (int fc = 0; fc < 2; ++fc)
        for (int r = 0; r < 4; ++r)
          acc[fr][fc][r] += __expf(sc[fr][fc][r]) * iz[r];
    }
  }
  for (int fr = 0; fr < 2; ++fr)
    for (int fc = 0; fc < 2; ++fc)
      for (int r = 0; r < 4; ++r) {
        int t = t0 + wr * 32 + fr * 16 + ((lane >> 4) << 2) + r;
        int s = s0 + wc * 32 + fc * 16 + (lane & 15);
        attn[(size_t)t * SRCN + s] = acc[fr][fc][r];
      }
}

// ---------------------------------------------------------------------------
// L4: dense output. One block per row (reversed), 512 threads.
// Phase 1: attn row -> LDS; pL[rank] table. Phase 2: pure stream.
// ---------------------------------------------------------------------------
__global__ __launch_bounds__(512) void out_kernel(
    const float* __restrict__ logits, const float4* __restrict__ rowc,
    const int* __restrict__ sperm, const u32* __restrict__ segmap,
    const u32* __restrict__ ustart, const float* __restrict__ attn,
    float* __restrict__ out) {
  __shared__ float aL[2048];
  __shared__ float pL[2048];
  const int t = (TGT - 1) - blockIdx.x;
  const int tid = threadIdx.x;
  float4 rc = rowc[t];
  const float K1 = rc.x, Ceps = rc.y, cc = rc.z;
  const f32x4* l4 = (const f32x4*)(logits + (size_t)t * NV);
  f32x4* o4 = (f32x4*)(out + (size_t)t * NTOT);
  const u32x4* m4 = (const u32x4*)segmap;

  *(float4*)&aL[tid * 4] = *(const float4*)&attn[(size_t)t * SRCN + tid * 4];
  __syncthreads();
  for (int r = tid; r < 2048; r += 512) {
    u32 u = ustart[r];
    if (u != 0xFFFFFFFFu) {
      int p = (int)(u & 0xFFFFu), n = (int)(u >> 16);
      float s = 0.f;
      for (int k = 0; k < n; ++k) s += aL[sperm[p + k]];
      pL[r] = cc * s;
    }
  }
  __syncthreads();

  auto psum = [&](u32 mv) -> float {
    return (mv == 0xFFFFFFFFu) ? Ceps : pL[mv & 0xFFFFu];
  };
  auto elem = [&](float v, bool d, u32 mv) -> float {
    float e = d ? __expf(v) : 0.f;
    return __logf(fmaf(e, K1, psum(mv)));
  };

  const f32x4 z4 = {0.f, 0.f, 0.f, 0.f};
#pragma unroll
  for (int pk = 0; pk < 4; ++pk) {
    int g0 = pk * 2048 + tid;
    int g1 = g0 + 512, g2 = g0 + 1024, g3 = g0 + 1536;
    u32x4 m0 = m4[g0], m1 = m4[g1], m2 = m4[g2], m3 = m4[g3];
    bool d0 = g0 < NV / 4, d1 = g1 < NV / 4, d2 = g2 < NV / 4, d3 = g3 < NV / 4;
    f32x4 v0 = d0 ? __builtin_nontemporal_load(&l4[g0]) : z4;
    f32x4 v1 = d1 ? __builtin_nontemporal_load(&l4[g1]) : z4;
    f32x4 v2 = d2 ? __builtin_nontemporal_load(&l4[g2]) : z4;
    f32x4 v3 = d3 ? __builtin_nontemporal_load(&l4[g3]) : z4;
    f32x4 o0, o1, o2, o3;
    o0.x = elem(v0.x, d0, m0.x); o0.y = elem(v0.y, d0, m0.y);
    o0.z = elem(v0.z, d0, m0.z); o0.w = elem(v0.w, d0, m0.w);
    o1.x = elem(v1.x, d1, m1.x); o1.y = elem(v1.y, d1, m1.y);
    o1.z = elem(v1.z, d1, m1.z); o1.w = elem(v1.w, d1, m1.w);
    o2.x = elem(v2.x, d2, m2.x); o2.y = elem(v2.y, d2, m2.y);
    o2.z = elem(v2.z, d2, m2.z); o2.w = elem(v2.w, d2, m2.w);
    o3.x = elem(v3.x, d3, m3.x); o3.y = elem(v3.y, d3, m3.y);
    o3.z = elem(v3.z, d3, m3.z); o3.w = elem(v3.w, d3, m3.w);
    __builtin_nontemporal_store(o0, &o4[g0]);
    __builtin_nontemporal_store(o1, &o4[g1]);
    __builtin_nontemporal_store(o2, &o4[g2]);
    __builtin_nontemporal_store(o3, &o4[g3]);
  }
  for (int g = 8192 + tid; g < NTOT / 4; g += 512) {
    u32x4 m = m4[g];
    f32x4 o;
    o.x = __logf(psum(m.x));
    o.y = __logf(psum(m.y));
    o.z = __logf(psum(m.z));
    o.w = __logf(psum(m.w));
    __builtin_nontemporal_store(o, &o4[g]);
  }
}

// ---------------------------------------------------------------------------
extern "C" void kernel_launch(void* const* d_in, const int* in_sizes, int n_in,
                              void* d_out, int out_size, void* d_ws, size_t ws_size,
                              hipStream_t stream) {
  const float* logits = (const float*)d_in[0];
  const int* ids      = (const int*)d_in[1];
  const float* src    = (const float*)d_in[2];
  const float* tgt    = (const float*)d_in[3];
  const float* w_q    = (const float*)d_in[4];
  const float* b_q    = (const float*)d_in[5];
  const float* w_k    = (const float*)d_in[6];
  const float* b_k    = (const float*)d_in[7];
  const float* w_ptr  = (const float*)d_in[8];
  const float* b_ptr  = (const float*)d_in[9];
  float* out = (float*)d_out;

  char* ws = (char*)d_ws;
  u16* Qb     = (u16*)(ws);                                       // 4 MiB
  u16* Kb     = (u16*)(ws + (size_t)4 * 1024 * 1024);             // 4 MiB
  float* Zinv = (float*)(ws + (size_t)8 * 1024 * 1024);           // 128 KiB
  float* attn = (float*)(ws + (size_t)8 * 1024 * 1024 + 131072);  // 16 MiB
  size_t tail_off = (size_t)8 * 1024 * 1024 + 131072 + (size_t)16 * 1024 * 1024;
  int* sperm   = (int*)(ws + tail_off);                      // 8 KiB
  u32* segmap  = (u32*)(ws + tail_off + 8192);               // 136 KiB
  u32* ustart  = (u32*)(ws + tail_off + 8192 + 136000);      // 8 KiB
  float4* rowc = (float4*)(ws + tail_off + 8192 + 136000 + 8192);  // 32 KiB

  fused_a_kernel<<<2305, 256, 0, stream>>>(logits, tgt, src, w_q, b_q, w_k, b_k,
                                           w_ptr, b_ptr, ids, Qb, Kb,
                                           sperm, segmap, ustart, rowc);
  zsum_kernel<<<dim3(16, 32), 256, 0, stream>>>(Qb, Kb, Zinv);
  attn_kernel<<<1024, 256, 0, stream>>>(Qb, Kb, Zinv, attn);
  out_kernel<<<TGT, 512, 0, stream>>>(logits, rowc, sperm, segmap, ustart, attn, out);
}